// Round 1
// 413.330 us; speedup vs baseline: 1.1188x; 1.1188x over previous
//
#include <hip/hip_runtime.h>
#include <stdint.h>

// ResBlock: GraphConv(64->128) -> BN -> ReLU -> GraphConv(128->128) -> BN
//           + (x @ Wlin^T + blin) residual -> ReLU.
// Runtime dtype probe (bf16 vs f32).
// R9: the gemm kernels' end-of-block fp32 atomics (400K ops into 8 cache
// lines) were theorized as the all-pipes-idle 75us signature. Fixes:
//  - gemm0/gemm1/final are persistent grid-stride blocks; BN stats are
//    accumulated in registers across chunks and flushed ONCE per block to
//    LINE-PADDED slots (sum[c*SPAD], 128B/channel -> 256 independent lines).
//  - weights / BN0 coefficients hoisted out of the chunk loop; T14-style
//    reg-prefetch of the next chunk overlaps staging with MFMA.
//  - pcount (k_phist) padded to a line per partition; CURPAD -> 32.
// Binning + aggregation kernels unchanged.

#define CIN 64
#define COUT 128
#define BN_EPS 1e-5f
#define CURPAD 32              // ints: one 128B line per cursor
#define PCPAD 32               // ints: one 128B line per pcount entry
#define SPAD 32                // floats: one 128B line per stats channel
#define PSH 10                 // partition = dst >> PSH  (1024 nodes)
#define PNODES (1 << PSH)
#define MAXP 128               // supports N <= 131072

typedef unsigned short u16;
typedef short short8 __attribute__((ext_vector_type(8)));
typedef float f32x4 __attribute__((ext_vector_type(4)));

__device__ __forceinline__ float bf2f(u16 u) {
    union { unsigned int i; float f; } v; v.i = ((unsigned int)u) << 16; return v.f;
}
__device__ __forceinline__ u16 f2bf(float f) {
    union { float f; unsigned int i; } v; v.f = f;
    unsigned int r = v.i + 0x7fffu + ((v.i >> 16) & 1u);  // RNE; finite inputs
    return (u16)(r >> 16);
}
__device__ __forceinline__ float lo16(unsigned int w) { return bf2f((u16)(w & 0xffffu)); }
__device__ __forceinline__ float hi16(unsigned int w) { return bf2f((u16)(w >> 16)); }

template<bool BF> __device__ __forceinline__ float ldf(const void* p, long i) {
    if (BF) return bf2f(((const u16*)p)[i]);
    return ((const float*)p)[i];
}
template<bool BF> __device__ __forceinline__ short8 ld8(const void* p, long i) {
    if (BF) return *(const short8*)((const u16*)p + i);
    const float* f = (const float*)p + i;
    short8 r;
#pragma unroll
    for (int j = 0; j < 8; ++j) r[j] = (short)f2bf(f[j]);
    return r;
}

// ---------------- dtype detection ----------------
__global__ void k_detect(const unsigned int* __restrict__ x, int* __restrict__ flag) {
    int lane = threadIdx.x;  // 64
    int cnt = 0;
#pragma unroll
    for (int i = 0; i < 8; ++i) {
        unsigned int w = x[lane * 8 + i];
        unsigned int e0 = (w >> 7) & 0xFFu, e1 = (w >> 23) & 0xFFu;
        cnt += (e0 >= 0x60u && e0 <= 0x8Eu);
        cnt += (e1 >= 0x60u && e1 <= 0x8Eu);
    }
    for (int o = 32; o; o >>= 1) cnt += __shfl_down(cnt, o);
    if (lane == 0) *flag = (cnt > 850) ? 1 : 0;   // 1 => bf16
}

// ---------------- partition build (partition = dst >> PSH) ----------------
__global__ __launch_bounds__(256) void k_phist(const int* __restrict__ dst,
                                               int* __restrict__ pcount, int E, int np) {
    __shared__ int h[MAXP];
    for (int i = threadIdx.x; i < np; i += 256) h[i] = 0;
    __syncthreads();
    int stride = gridDim.x * 256;
    for (int e = blockIdx.x * 256 + threadIdx.x; e < E; e += stride)
        atomicAdd(&h[dst[e] >> PSH], 1);
    __syncthreads();
    for (int i = threadIdx.x; i < np; i += 256)
        if (h[i]) atomicAdd(&pcount[i * PCPAD], h[i]);
}

__global__ void k_pscan(const int* __restrict__ pcount, int* __restrict__ pstart,
                        int* __restrict__ pcursor, int np, int E) {
    __shared__ int s[MAXP];
    int t = threadIdx.x;  // 128 threads
    int v = (t < np) ? pcount[t * PCPAD] : 0;
    s[t] = v; __syncthreads();
    for (int o = 1; o < MAXP; o <<= 1) {
        int u = (t >= o) ? s[t - o] : 0;
        __syncthreads(); s[t] += u; __syncthreads();
    }
    if (t < np) {
        int ex = s[t] - v;
        pstart[t] = ex;
        pcursor[t * CURPAD] = ex;
    }
    if (t == 0) pstart[np] = E;
}

// One 4096-edge tile per block. Per-(block,partition) contiguous runs ->
// each barr cache line written by ~one block (no cross-block false sharing).
// rec = (dst & (PNODES-1)) << 20 | src   (src < 2^20)
__global__ __launch_bounds__(256) void k_pfill(const int* __restrict__ src,
        const int* __restrict__ dst, int* __restrict__ pcursor,
        unsigned int* __restrict__ barr, int E, int np) {
    __shared__ int cnt[MAXP], gb[MAXP], loc[MAXP];
    int tid = threadIdx.x;
    int base = blockIdx.x * 4096;
    for (int i = tid; i < np; i += 256) { cnt[i] = 0; loc[i] = 0; }
    __syncthreads();
    int pk[16]; unsigned int rec[16];
#pragma unroll
    for (int k = 0; k < 16; ++k) {
        int e = base + k * 256 + tid;
        if (e < E) {
            int d = dst[e];
            pk[k] = d >> PSH;
            rec[k] = ((unsigned int)(d & (PNODES - 1)) << 20) | (unsigned int)src[e];
            atomicAdd(&cnt[pk[k]], 1);
        } else pk[k] = -1;
    }
    __syncthreads();
    for (int i = tid; i < np; i += 256)
        if (cnt[i]) gb[i] = atomicAdd(&pcursor[i * CURPAD], cnt[i]);
    __syncthreads();
#pragma unroll
    for (int k = 0; k < 16; ++k) {
        if (pk[k] >= 0) {
            int off = atomicAdd(&loc[pk[k]], 1);
            barr[gb[pk[k]] + off] = rec[k];
        }
    }
}

// Block per partition: LDS counting sort -> node-sorted csr + row_start.
__global__ __launch_bounds__(256) void k_psort(const unsigned int* __restrict__ barr,
        const int* __restrict__ pstart, int* __restrict__ csr,
        int* __restrict__ row_start, int n, int np, int E) {
    __shared__ int hist[PNODES], curs[PNODES], tsum[256];
    int tid = threadIdx.x;
    int p = blockIdx.x;
    int e0 = pstart[p], e1 = pstart[p + 1];
    int node0 = p << PSH;
#pragma unroll
    for (int j = 0; j < PNODES / 256; ++j) hist[tid + j * 256] = 0;
    __syncthreads();
    for (int t = e0 + tid; t < e1; t += 256)
        atomicAdd(&hist[barr[t] >> 20], 1);
    __syncthreads();
    // block scan over PNODES=1024 entries (4 per thread)
    int s0 = hist[tid * 4], s1 = hist[tid * 4 + 1], s2 = hist[tid * 4 + 2], s3 = hist[tid * 4 + 3];
    int sum4 = s0 + s1 + s2 + s3;
    tsum[tid] = sum4; __syncthreads();
    for (int o = 1; o < 256; o <<= 1) {
        int u = (tid >= o) ? tsum[tid - o] : 0;
        __syncthreads(); tsum[tid] += u; __syncthreads();
    }
    int bexc = tsum[tid] - sum4;
    int off0 = bexc, off1 = bexc + s0, off2 = off1 + s1, off3 = off2 + s2;
    curs[tid * 4] = off0; curs[tid * 4 + 1] = off1;
    curs[tid * 4 + 2] = off2; curs[tid * 4 + 3] = off3;
    int nd = node0 + tid * 4;
    if (nd < n)     row_start[nd]     = e0 + off0;
    if (nd + 1 < n) row_start[nd + 1] = e0 + off1;
    if (nd + 2 < n) row_start[nd + 2] = e0 + off2;
    if (nd + 3 < n) row_start[nd + 3] = e0 + off3;
    if (p == np - 1 && tid == 0) row_start[n] = E;
    __syncthreads();
    for (int t = e0 + tid; t < e1; t += 256) {
        unsigned int rec = barr[t];
        int pos = atomicAdd(&curs[rec >> 20], 1);
        csr[e0 + pos] = (int)(rec & 0xFFFFF);
    }
}

// ---------------- aggregation (pull, wave per node, coalesced rows) -------
template<bool BF>
__device__ __forceinline__ void agg0_impl(const void* x, const int* rs, const int* csr,
                                          u16* agg, int n) {
    int i = blockIdx.x * 4 + (threadIdx.x >> 6);
    if (i >= n) return;
    int lane = threadIdx.x & 63;
    int h = lane >> 5, cp = lane & 31;
    int b = rs[i], e = rs[i + 1];
    float a0 = 0.f, a1 = 0.f, b0 = 0.f, b1 = 0.f;
    int t = b + h;
    for (; t + 2 < e; t += 4) {
        int j0 = csr[t], j1 = csr[t + 2];
        if (BF) {
            unsigned int w0 = ((const unsigned int*)x)[(long)j0 * 32 + cp];
            unsigned int w1 = ((const unsigned int*)x)[(long)j1 * 32 + cp];
            a0 += lo16(w0); a1 += hi16(w0);
            b0 += lo16(w1); b1 += hi16(w1);
        } else {
            float2 w0 = ((const float2*)x)[(long)j0 * 32 + cp];
            float2 w1 = ((const float2*)x)[(long)j1 * 32 + cp];
            a0 += w0.x; a1 += w0.y;
            b0 += w1.x; b1 += w1.y;
        }
    }
    for (; t < e; t += 2) {
        int j0 = csr[t];
        if (BF) {
            unsigned int w0 = ((const unsigned int*)x)[(long)j0 * 32 + cp];
            a0 += lo16(w0); a1 += hi16(w0);
        } else {
            float2 w0 = ((const float2*)x)[(long)j0 * 32 + cp];
            a0 += w0.x; a1 += w0.y;
        }
    }
    a0 += b0; a1 += b1;
    a0 += __shfl_xor(a0, 32);
    a1 += __shfl_xor(a1, 32);
    if (h == 0) {
        unsigned int o = (unsigned int)f2bf(a0) | ((unsigned int)f2bf(a1) << 16);
        ((unsigned int*)agg)[(long)i * 32 + cp] = o;
    }
}

__global__ __launch_bounds__(256) void k_agg0(const int* __restrict__ flag,
        const void* x, const int* __restrict__ rs, const int* __restrict__ csr,
        u16* __restrict__ agg, int n) {
    if (*flag) agg0_impl<true >(x, rs, csr, agg, n);
    else       agg0_impl<false>(x, rs, csr, agg, n);
}

// agg1: gathers relu(bn0(y0_raw)); scale/shift applied on the fly. bf16 internal.
__global__ __launch_bounds__(256) void k_agg1(const u16* __restrict__ y0,
        const int* __restrict__ rs, const int* __restrict__ csr,
        const float* __restrict__ scale, const float* __restrict__ shift,
        u16* __restrict__ agg, int n) {
    int i = blockIdx.x * 4 + (threadIdx.x >> 6);
    if (i >= n) return;
    int lane = threadIdx.x & 63;
    int c0 = 2 * lane;
    float s0 = scale[c0], s1 = scale[c0 + 1];
    float h0 = shift[c0], h1 = shift[c0 + 1];
    const unsigned int* y32 = (const unsigned int*)y0;
    int b = rs[i], e = rs[i + 1];
    float a0 = 0.f, a1 = 0.f, b0 = 0.f, b1 = 0.f;
    float c0a = 0.f, c1a = 0.f, d0 = 0.f, d1 = 0.f;
    int t = b;
    for (; t + 4 <= e; t += 4) {
        int j0 = csr[t], j1 = csr[t + 1], j2 = csr[t + 2], j3 = csr[t + 3];
        unsigned int w0 = y32[(long)j0 * 64 + lane];
        unsigned int w1 = y32[(long)j1 * 64 + lane];
        unsigned int w2 = y32[(long)j2 * 64 + lane];
        unsigned int w3 = y32[(long)j3 * 64 + lane];
        a0  += fmaxf(lo16(w0) * s0 + h0, 0.f); a1  += fmaxf(hi16(w0) * s1 + h1, 0.f);
        b0  += fmaxf(lo16(w1) * s0 + h0, 0.f); b1  += fmaxf(hi16(w1) * s1 + h1, 0.f);
        c0a += fmaxf(lo16(w2) * s0 + h0, 0.f); c1a += fmaxf(hi16(w2) * s1 + h1, 0.f);
        d0  += fmaxf(lo16(w3) * s0 + h0, 0.f); d1  += fmaxf(hi16(w3) * s1 + h1, 0.f);
    }
    for (; t < e; ++t) {
        unsigned int w0 = y32[(long)csr[t] * 64 + lane];
        a0 += fmaxf(lo16(w0) * s0 + h0, 0.f); a1 += fmaxf(hi16(w0) * s1 + h1, 0.f);
    }
    float s0t = (a0 + b0) + (c0a + d0);
    float s1t = (a1 + b1) + (c1a + d1);
    ((unsigned int*)agg)[(long)i * 64 + lane] =
        (unsigned int)f2bf(s0t) | ((unsigned int)f2bf(s1t) << 16);
}

// ---------------- GEMM0: y0 = [x|agg0] @ [Wr0;Wn0]^T, fused stats ----------
// Persistent grid-stride; stats in regs; one padded atomic per channel/block.
template<bool BF>
__device__ __forceinline__ void gemm0_impl(const void* x, const u16* agg,
                                           const void* Wr, const void* Wn,
                                           u16* y0, float* sumP, float* sqP,
                                           int n, int nch, u16* lds) {
    const int ST = 130;
    int tid = threadIdx.x;
    int wave = tid >> 6, lane = tid & 63, lr = lane & 15, q = lane >> 4;

    short8 wf[2][4];
#pragma unroll
    for (int i = 0; i < 2; ++i) {
        int c = (2 * wave + i) * 16 + lr;
#pragma unroll
        for (int ks = 0; ks < 4; ++ks) {
            const void* W = (ks < 2) ? Wr : Wn;
            wf[i][ks] = ld8<BF>(W, (long)c * CIN + (ks & 1) * 32 + q * 8);
        }
    }

    const int rowb = tid >> 3, wb = tid & 7;    // bf16 64-wide rows: 2/thread
    const int rowf = tid >> 4, wfc = tid & 15;  // f32 64-wide rows: 4/thread
    short8 rbx[2]; float4 rfx[4]; short8 rag[2];

    auto regload = [&](long chunk0) {
        if (BF) {
#pragma unroll
            for (int i = 0; i < 2; ++i) {
                long rg = chunk0 + rowb + i * 32; if (rg > n - 1) rg = n - 1;
                rbx[i] = *(const short8*)((const u16*)x + rg * CIN + wb * 8);
            }
        } else {
#pragma unroll
            for (int i = 0; i < 4; ++i) {
                long rg = chunk0 + rowf + i * 16; if (rg > n - 1) rg = n - 1;
                rfx[i] = *(const float4*)((const float*)x + rg * CIN + wfc * 4);
            }
        }
#pragma unroll
        for (int i = 0; i < 2; ++i) {
            long rg = chunk0 + rowb + i * 32; if (rg > n - 1) rg = n - 1;
            rag[i] = *(const short8*)(agg + rg * CIN + wb * 8);
        }
    };

    float st[2] = {0.f, 0.f}, sq[2] = {0.f, 0.f};
    int ch = blockIdx.x;
    if (ch < nch) regload((long)ch * 64);
    for (; ch < nch; ch += gridDim.x) {
        long chunk0 = (long)ch * 64;
        __syncthreads();                        // prev compute done with LDS
        if (BF) {
#pragma unroll
            for (int i = 0; i < 2; ++i)
                *(short8*)(lds + (rowb + i * 32) * ST + wb * 8) = rbx[i];
        } else {
#pragma unroll
            for (int i = 0; i < 4; ++i) {
                u16* d = lds + (rowf + i * 16) * ST + wfc * 4;
                d[0] = f2bf(rfx[i].x); d[1] = f2bf(rfx[i].y);
                d[2] = f2bf(rfx[i].z); d[3] = f2bf(rfx[i].w);
            }
        }
#pragma unroll
        for (int i = 0; i < 2; ++i)
            *(short8*)(lds + (rowb + i * 32) * ST + 64 + wb * 8) = rag[i];
        __syncthreads();
        long nxt = (long)ch + gridDim.x;        // T14: issue next loads now
        if (nxt < nch) regload(nxt * 64);

#pragma unroll
        for (int t = 0; t < 4; ++t) {
            short8 a[4];
#pragma unroll
            for (int ks = 0; ks < 4; ++ks)
                a[ks] = *(const short8*)(lds + (t * 16 + lr) * ST + ks * 32 + q * 8);
#pragma unroll
            for (int i = 0; i < 2; ++i) {
                f32x4 acc = {0.f, 0.f, 0.f, 0.f};
#pragma unroll
                for (int ks = 0; ks < 4; ++ks)
                    acc = __builtin_amdgcn_mfma_f32_16x16x32_bf16(a[ks], wf[i][ks], acc, 0, 0, 0);
                int c = (2 * wave + i) * 16 + lr;
#pragma unroll
                for (int r = 0; r < 4; ++r) {
                    long row = chunk0 + t * 16 + q * 4 + r;
                    if (row < n) {
                        y0[row * COUT + c] = f2bf(acc[r]);   // b0 cancels in BN
                        st[i] += acc[r]; sq[i] += acc[r] * acc[r];
                    }
                }
            }
        }
    }
#pragma unroll
    for (int i = 0; i < 2; ++i) {
        st[i] += __shfl_xor(st[i], 16); st[i] += __shfl_xor(st[i], 32);
        sq[i] += __shfl_xor(sq[i], 16); sq[i] += __shfl_xor(sq[i], 32);
    }
    if (q == 0) {
#pragma unroll
        for (int i = 0; i < 2; ++i) {
            int c = (2 * wave + i) * 16 + lr;
            atomicAdd(&sumP[c * SPAD], st[i]);
            atomicAdd(&sqP[c * SPAD], sq[i]);
        }
    }
}

__global__ __launch_bounds__(256) void k_gemm0(const int* __restrict__ flag,
        const void* x, const u16* __restrict__ agg, const void* Wr, const void* Wn,
        u16* __restrict__ y0, float* __restrict__ sumP, float* __restrict__ sqP,
        int n, int nch) {
    __shared__ u16 lds[64 * 130];
    if (*flag) gemm0_impl<true >(x, agg, Wr, Wn, y0, sumP, sqP, n, nch, lds);
    else       gemm0_impl<false>(x, agg, Wr, Wn, y0, sumP, sqP, n, nch, lds);
}

// ---------------- GEMM1: y1 = [relu(bn0(y0))|agg1] @ [Wr1;Wn1]^T, stats ----
template<bool BF>
__device__ __forceinline__ void gemm1_impl(const u16* y0, const u16* agg,
                                           const void* Wr, const void* Wn,
                                           const float* sc0, const float* sh0,
                                           u16* y1, float* sumP, float* sqP,
                                           int n, int nch, u16* lds) {
    const int ST = 258;
    int tid = threadIdx.x;
    int wave = tid >> 6, lane = tid & 63, lr = lane & 15, q = lane >> 4;

    short8 wf[2][8];
#pragma unroll
    for (int i = 0; i < 2; ++i) {
        int c = (2 * wave + i) * 16 + lr;
#pragma unroll
        for (int ks = 0; ks < 8; ++ks) {
            const void* W = (ks < 4) ? Wr : Wn;
            wf[i][ks] = ld8<BF>(W, (long)c * COUT + (ks & 3) * 32 + q * 8);
        }
    }

    const int rowy = tid >> 4, wy = tid & 15;   // 128-wide rows: 4/thread
    float s8[8], h8[8];                         // BN0 coeffs: loop-invariant slice
#pragma unroll
    for (int j = 0; j < 8; ++j) { s8[j] = sc0[wy * 8 + j]; h8[j] = sh0[wy * 8 + j]; }

    short8 ry[4], rag[4];
    auto regload = [&](long chunk0) {
#pragma unroll
        for (int i = 0; i < 4; ++i) {
            long rg = chunk0 + rowy + i * 16; if (rg > n - 1) rg = n - 1;
            ry[i]  = *(const short8*)(y0  + rg * COUT + wy * 8);
            rag[i] = *(const short8*)(agg + rg * COUT + wy * 8);
        }
    };

    float st[2] = {0.f, 0.f}, sq[2] = {0.f, 0.f};
    int ch = blockIdx.x;
    if (ch < nch) regload((long)ch * 64);
    for (; ch < nch; ch += gridDim.x) {
        long chunk0 = (long)ch * 64;
        __syncthreads();
#pragma unroll
        for (int i = 0; i < 4; ++i) {
            short8 o;
#pragma unroll
            for (int j = 0; j < 8; ++j)
                o[j] = (short)f2bf(fmaxf(bf2f((u16)ry[i][j]) * s8[j] + h8[j], 0.f));
            *(short8*)(lds + (rowy + i * 16) * ST + wy * 8) = o;
            *(short8*)(lds + (rowy + i * 16) * ST + 128 + wy * 8) = rag[i];
        }
        __syncthreads();
        long nxt = (long)ch + gridDim.x;
        if (nxt < nch) regload(nxt * 64);

#pragma unroll
        for (int t = 0; t < 4; ++t) {
            short8 a[8];
#pragma unroll
            for (int ks = 0; ks < 8; ++ks)
                a[ks] = *(const short8*)(lds + (t * 16 + lr) * ST + ks * 32 + q * 8);
#pragma unroll
            for (int i = 0; i < 2; ++i) {
                f32x4 acc = {0.f, 0.f, 0.f, 0.f};
#pragma unroll
                for (int ks = 0; ks < 8; ++ks)
                    acc = __builtin_amdgcn_mfma_f32_16x16x32_bf16(a[ks], wf[i][ks], acc, 0, 0, 0);
                int c = (2 * wave + i) * 16 + lr;
#pragma unroll
                for (int r = 0; r < 4; ++r) {
                    long row = chunk0 + t * 16 + q * 4 + r;
                    if (row < n) {
                        y1[row * COUT + c] = f2bf(acc[r]);   // b1 cancels in BN
                        st[i] += acc[r]; sq[i] += acc[r] * acc[r];
                    }
                }
            }
        }
    }
#pragma unroll
    for (int i = 0; i < 2; ++i) {
        st[i] += __shfl_xor(st[i], 16); st[i] += __shfl_xor(st[i], 32);
        sq[i] += __shfl_xor(sq[i], 16); sq[i] += __shfl_xor(sq[i], 32);
    }
    if (q == 0) {
#pragma unroll
        for (int i = 0; i < 2; ++i) {
            int c = (2 * wave + i) * 16 + lr;
            atomicAdd(&sumP[c * SPAD], st[i]);
            atomicAdd(&sqP[c * SPAD], sq[i]);
        }
    }
}

__global__ __launch_bounds__(256) void k_gemm1(const int* __restrict__ flag,
        const u16* __restrict__ y0, const u16* __restrict__ agg,
        const void* Wr, const void* Wn,
        const float* __restrict__ sc0, const float* __restrict__ sh0,
        u16* y1_bf /*=d_out*/, u16* y1_ws,
        float* __restrict__ sumP, float* __restrict__ sqP, int n, int nch) {
    __shared__ u16 lds[64 * 258];
    u16* y1 = *flag ? y1_bf : y1_ws;
    if (*flag) gemm1_impl<true >(y0, agg, Wr, Wn, sc0, sh0, y1, sumP, sqP, n, nch, lds);
    else       gemm1_impl<false>(y0, agg, Wr, Wn, sc0, sh0, y1, sumP, sqP, n, nch, lds);
}

// ---------------- BN finalize (reads line-padded stats) ----------------
__global__ void k_bnfin(const int* __restrict__ flag,
                        const float* __restrict__ sumP, const float* __restrict__ sqP,
                        const void* g, const void* be,
                        float* __restrict__ scale, float* __restrict__ shift, int n) {
    int c = threadIdx.x;
    bool bf = (*flag != 0);
    float inv = 1.f / (float)n;
    float mu = sumP[c * SPAD] * inv;
    float var = fmaxf(sqP[c * SPAD] * inv - mu * mu, 0.f);
    float gv = bf ? bf2f(((const u16*)g)[c]) : ((const float*)g)[c];
    float bv = bf ? bf2f(((const u16*)be)[c]) : ((const float*)be)[c];
    float sc = gv * rsqrtf(var + BN_EPS);
    scale[c] = sc;
    shift[c] = bv - mu * sc;
}

// ---------------- final: out = relu(bn1(y1) + x@Wlin^T + blin) ------------
template<bool BF>
__device__ __forceinline__ void final_impl(const void* x, const u16* y1,
                                           const void* Wlin, const void* blin,
                                           const float* sc, const float* sh,
                                           void* out, int n, int nch, u16* lds) {
    const int ST = 194;
    int tid = threadIdx.x;
    int wave = tid >> 6, lane = tid & 63, lr = lane & 15, q = lane >> 4;

    short8 wf[2][2];
    float blc[2], scc[2], shc[2];
#pragma unroll
    for (int i = 0; i < 2; ++i) {
        int c = (2 * wave + i) * 16 + lr;
#pragma unroll
        for (int ks = 0; ks < 2; ++ks)
            wf[i][ks] = ld8<BF>(Wlin, (long)c * CIN + ks * 32 + q * 8);
        blc[i] = ldf<BF>(blin, c);
        scc[i] = sc[c]; shc[i] = sh[c];
    }

    const int rowb = tid >> 3, wb = tid & 7;
    const int rowf = tid >> 4, wfc = tid & 15;
    const int rowy = tid >> 4, wy = tid & 15;
    short8 rbx[2]; float4 rfx[4]; short8 ry[4];

    auto regload = [&](long chunk0) {
        if (BF) {
#pragma unroll
            for (int i = 0; i < 2; ++i) {
                long rg = chunk0 + rowb + i * 32; if (rg > n - 1) rg = n - 1;
                rbx[i] = *(const short8*)((const u16*)x + rg * CIN + wb * 8);
            }
        } else {
#pragma unroll
            for (int i = 0; i < 4; ++i) {
                long rg = chunk0 + rowf + i * 16; if (rg > n - 1) rg = n - 1;
                rfx[i] = *(const float4*)((const float*)x + rg * CIN + wfc * 4);
            }
        }
#pragma unroll
        for (int i = 0; i < 4; ++i) {
            long rg = chunk0 + rowy + i * 16; if (rg > n - 1) rg = n - 1;
            ry[i] = *(const short8*)(y1 + rg * COUT + wy * 8);
        }
    };

    int ch = blockIdx.x;
    if (ch < nch) regload((long)ch * 64);
    for (; ch < nch; ch += gridDim.x) {
        long chunk0 = (long)ch * 64;
        __syncthreads();
        if (BF) {
#pragma unroll
            for (int i = 0; i < 2; ++i)
                *(short8*)(lds + (rowb + i * 32) * ST + wb * 8) = rbx[i];
        } else {
#pragma unroll
            for (int i = 0; i < 4; ++i) {
                u16* d = lds + (rowf + i * 16) * ST + wfc * 4;
                d[0] = f2bf(rfx[i].x); d[1] = f2bf(rfx[i].y);
                d[2] = f2bf(rfx[i].z); d[3] = f2bf(rfx[i].w);
            }
        }
#pragma unroll
        for (int i = 0; i < 4; ++i)
            *(short8*)(lds + (rowy + i * 16) * ST + 64 + wy * 8) = ry[i];
        __syncthreads();
        long nxt = (long)ch + gridDim.x;
        if (nxt < nch) regload(nxt * 64);

#pragma unroll
        for (int t = 0; t < 4; ++t) {
            short8 a[2];
#pragma unroll
            for (int ks = 0; ks < 2; ++ks)
                a[ks] = *(const short8*)(lds + (t * 16 + lr) * ST + ks * 32 + q * 8);
#pragma unroll
            for (int i = 0; i < 2; ++i) {
                f32x4 acc = {0.f, 0.f, 0.f, 0.f};
                acc = __builtin_amdgcn_mfma_f32_16x16x32_bf16(a[0], wf[i][0], acc, 0, 0, 0);
                acc = __builtin_amdgcn_mfma_f32_16x16x32_bf16(a[1], wf[i][1], acc, 0, 0, 0);
                int c = (2 * wave + i) * 16 + lr;
#pragma unroll
                for (int r = 0; r < 4; ++r) {
                    long row = chunk0 + t * 16 + q * 4 + r;
                    if (row < n) {
                        float yv = bf2f(lds[(t * 16 + q * 4 + r) * ST + 64 + c]);
                        float v = acc[r] + blc[i] + yv * scc[i] + shc[i];
                        v = fmaxf(v, 0.f);
                        if (BF) ((u16*)out)[row * COUT + c] = f2bf(v);
                        else    ((float*)out)[row * COUT + c] = v;
                    }
                }
            }
        }
    }
}

__global__ __launch_bounds__(256) void k_final(const int* __restrict__ flag,
        const void* x, const void* Wlin, const void* blin,
        const u16* y1_bf /*=d_out*/, const u16* y1_ws,
        const float* __restrict__ sc, const float* __restrict__ sh,
        void* out, int n, int nch) {
    __shared__ u16 lds[64 * 194];
    const u16* y1 = *flag ? y1_bf : y1_ws;
    if (*flag) final_impl<true >(x, y1, Wlin, blin, sc, sh, out, n, nch, lds);
    else       final_impl<false>(x, y1, Wlin, blin, sc, sh, out, n, nch, lds);
}

extern "C" void kernel_launch(void* const* d_in, const int* in_sizes, int n_in,
                              void* d_out, int out_size, void* d_ws, size_t ws_size,
                              hipStream_t stream) {
    (void)n_in; (void)out_size; (void)ws_size;
    const void* x    = d_in[0];
    const int*  ei   = (const int*)d_in[1];
    const void* Wr0  = d_in[2];
    const void* Wn0  = d_in[3];
    /* b0 dropped: BN-invariant */
    const void* g0   = d_in[5];
    const void* be0  = d_in[6];
    const void* Wr1  = d_in[7];
    const void* Wn1  = d_in[8];
    /* b1 dropped */
    const void* g1   = d_in[10];
    const void* be1  = d_in[11];
    const void* Wlin = d_in[12];
    const void* blin = d_in[13];

    const int N = in_sizes[0] / CIN;
    const int E = in_sizes[1] / 2;
    const int* src = ei;
    const int* dst = ei + E;
    const int NP = (N + PNODES - 1) >> PSH;   // partitions (<= MAXP for N <= 131072)

    // ---- workspace carve (256B aligned); f32-only region LAST ----
    char* base = (char*)d_ws;
    size_t off = 0;
    auto carve = [&](size_t bytes) -> void* {
        void* p = base + off;
        off = (off + bytes + 255) & ~(size_t)255;
        return p;
    };
    int*   flag      = (int*)carve(256);
    int*   pcount    = (int*)carve(MAXP * PCPAD * sizeof(int));
    int*   pstart    = (int*)carve((MAXP + 1) * sizeof(int));
    int*   pcursor   = (int*)carve(MAXP * CURPAD * sizeof(int));
    float* statsP    = (float*)carve(4 * 128 * SPAD * sizeof(float)); // padded sum0,sq0,sum1,sq1
    float* scsh      = (float*)carve(512 * sizeof(float));  // scale0,shift0,scale1,shift1
    int*   row_start = (int*)carve((size_t)(N + 1) * sizeof(int));
    unsigned int* barr = (unsigned int*)carve((size_t)E * sizeof(int));
    int*   csr       = (int*)carve((size_t)E * sizeof(int));
    u16*   aggu      = (u16*)carve((size_t)N * COUT * sizeof(u16)); // agg0 aliases agg1
    u16*   y0        = (u16*)carve((size_t)N * COUT * sizeof(u16));
    u16*   y1_ws     = (u16*)carve((size_t)N * COUT * sizeof(u16)); // f32 mode only

    float* sum0P = statsP;
    float* sq0P  = statsP + 128 * SPAD;
    float* sum1P = statsP + 256 * SPAD;
    float* sq1P  = statsP + 384 * SPAD;

    hipMemsetAsync(pcount, 0, MAXP * PCPAD * sizeof(int), stream);
    hipMemsetAsync(statsP, 0, 4 * 128 * SPAD * sizeof(float), stream);

    const int nwb = (N + 3) / 4;        // wave-per-node blocks
    const int nch = (N + 63) / 64;      // 64-row chunks for dense kernels
    const int ntl = (E + 4095) / 4096;  // pfill tiles
    const int G   = nch < 1024 ? nch : 1024;  // persistent gemm grid

    k_detect<<<1, 64, 0, stream>>>((const unsigned int*)x, flag);

    k_phist<<<256, 256, 0, stream>>>(dst, pcount, E, NP);
    k_pscan<<<1, MAXP, 0, stream>>>(pcount, pstart, pcursor, NP, E);
    k_pfill<<<ntl, 256, 0, stream>>>(src, dst, pcursor, barr, E, NP);
    k_psort<<<NP, 256, 0, stream>>>(barr, pstart, csr, row_start, N, NP, E);

    k_agg0 <<<nwb, 256, 0, stream>>>(flag, x, row_start, csr, aggu, N);
    k_gemm0<<<G, 256, 0, stream>>>(flag, x, aggu, Wr0, Wn0, y0,
                                   sum0P, sq0P, N, nch);
    k_bnfin<<<1, 128, 0, stream>>>(flag, sum0P, sq0P, g0, be0,
                                   scsh, scsh + 128, N);

    k_agg1 <<<nwb, 256, 0, stream>>>(y0, row_start, csr, scsh, scsh + 128, aggu, N);
    k_gemm1<<<G, 256, 0, stream>>>(flag, y0, aggu, Wr1, Wn1, scsh, scsh + 128,
                                   (u16*)d_out, y1_ws, sum1P, sq1P, N, nch);
    k_bnfin<<<1, 128, 0, stream>>>(flag, sum1P, sq1P, g1, be1,
                                   scsh + 256, scsh + 384, N);

    k_final<<<G, 256, 0, stream>>>(flag, x, Wlin, blin,
                                   (const u16*)d_out, y1_ws,
                                   scsh + 256, scsh + 384, d_out, N, nch);
}

// Round 2
// 396.999 us; speedup vs baseline: 1.1648x; 1.0411x over previous
//
#include <hip/hip_runtime.h>
#include <stdint.h>

// ResBlock: GraphConv(64->128) -> BN -> ReLU -> GraphConv(128->128) -> BN
//           + (x @ Wlin^T + blin) residual -> ReLU.
// Runtime dtype probe (bf16 vs f32).
// R10: k_agg1 was VALU-co-limited (54% VALUBusy = 40us of the 73.6us):
// per-edge BN fma+relu and per-lane 64-bit addressing dominated. Fixes:
//  - k_y0p: one streaming pass materializes y0p = relu(bn0(y0)) IN-PLACE
//    (consumed 17x: 16 gathered reads + gemm1 root input). agg1 and gemm1
//    no longer apply BN coefficients.
//  - agg kernels restructured to dwordx4 gathers: a 16-lane (agg1) / 8-lane
//    (agg0-bf16) group owns one edge slot and loads 16B/lane -> 4-8x fewer
//    VMEM instrs + address computes; slot partials merged via shfl_xor.
// R9 (kept): persistent gemm blocks, register BN stats, line-padded stat
// atomics, reg-prefetch double buffering. Binning kernels unchanged.

#define CIN 64
#define COUT 128
#define BN_EPS 1e-5f
#define CURPAD 32              // ints: one 128B line per cursor
#define PCPAD 32               // ints: one 128B line per pcount entry
#define SPAD 32                // floats: one 128B line per stats channel
#define PSH 10                 // partition = dst >> PSH  (1024 nodes)
#define PNODES (1 << PSH)
#define MAXP 128               // supports N <= 131072

typedef unsigned short u16;
typedef short short8 __attribute__((ext_vector_type(8)));
typedef float f32x4 __attribute__((ext_vector_type(4)));

__device__ __forceinline__ float bf2f(u16 u) {
    union { unsigned int i; float f; } v; v.i = ((unsigned int)u) << 16; return v.f;
}
__device__ __forceinline__ u16 f2bf(float f) {
    union { float f; unsigned int i; } v; v.f = f;
    unsigned int r = v.i + 0x7fffu + ((v.i >> 16) & 1u);  // RNE; finite inputs
    return (u16)(r >> 16);
}
__device__ __forceinline__ float lo16(unsigned int w) { return bf2f((u16)(w & 0xffffu)); }
__device__ __forceinline__ float hi16(unsigned int w) { return bf2f((u16)(w >> 16)); }

template<bool BF> __device__ __forceinline__ float ldf(const void* p, long i) {
    if (BF) return bf2f(((const u16*)p)[i]);
    return ((const float*)p)[i];
}
template<bool BF> __device__ __forceinline__ short8 ld8(const void* p, long i) {
    if (BF) return *(const short8*)((const u16*)p + i);
    const float* f = (const float*)p + i;
    short8 r;
#pragma unroll
    for (int j = 0; j < 8; ++j) r[j] = (short)f2bf(f[j]);
    return r;
}

// ---------------- dtype detection ----------------
__global__ void k_detect(const unsigned int* __restrict__ x, int* __restrict__ flag) {
    int lane = threadIdx.x;  // 64
    int cnt = 0;
#pragma unroll
    for (int i = 0; i < 8; ++i) {
        unsigned int w = x[lane * 8 + i];
        unsigned int e0 = (w >> 7) & 0xFFu, e1 = (w >> 23) & 0xFFu;
        cnt += (e0 >= 0x60u && e0 <= 0x8Eu);
        cnt += (e1 >= 0x60u && e1 <= 0x8Eu);
    }
    for (int o = 32; o; o >>= 1) cnt += __shfl_down(cnt, o);
    if (lane == 0) *flag = (cnt > 850) ? 1 : 0;   // 1 => bf16
}

// ---------------- partition build (partition = dst >> PSH) ----------------
__global__ __launch_bounds__(256) void k_phist(const int* __restrict__ dst,
                                               int* __restrict__ pcount, int E, int np) {
    __shared__ int h[MAXP];
    for (int i = threadIdx.x; i < np; i += 256) h[i] = 0;
    __syncthreads();
    int stride = gridDim.x * 256;
    for (int e = blockIdx.x * 256 + threadIdx.x; e < E; e += stride)
        atomicAdd(&h[dst[e] >> PSH], 1);
    __syncthreads();
    for (int i = threadIdx.x; i < np; i += 256)
        if (h[i]) atomicAdd(&pcount[i * PCPAD], h[i]);
}

__global__ void k_pscan(const int* __restrict__ pcount, int* __restrict__ pstart,
                        int* __restrict__ pcursor, int np, int E) {
    __shared__ int s[MAXP];
    int t = threadIdx.x;  // 128 threads
    int v = (t < np) ? pcount[t * PCPAD] : 0;
    s[t] = v; __syncthreads();
    for (int o = 1; o < MAXP; o <<= 1) {
        int u = (t >= o) ? s[t - o] : 0;
        __syncthreads(); s[t] += u; __syncthreads();
    }
    if (t < np) {
        int ex = s[t] - v;
        pstart[t] = ex;
        pcursor[t * CURPAD] = ex;
    }
    if (t == 0) pstart[np] = E;
}

// One 4096-edge tile per block. Per-(block,partition) contiguous runs ->
// each barr cache line written by ~one block (no cross-block false sharing).
// rec = (dst & (PNODES-1)) << 20 | src   (src < 2^20)
__global__ __launch_bounds__(256) void k_pfill(const int* __restrict__ src,
        const int* __restrict__ dst, int* __restrict__ pcursor,
        unsigned int* __restrict__ barr, int E, int np) {
    __shared__ int cnt[MAXP], gb[MAXP], loc[MAXP];
    int tid = threadIdx.x;
    int base = blockIdx.x * 4096;
    for (int i = tid; i < np; i += 256) { cnt[i] = 0; loc[i] = 0; }
    __syncthreads();
    int pk[16]; unsigned int rec[16];
#pragma unroll
    for (int k = 0; k < 16; ++k) {
        int e = base + k * 256 + tid;
        if (e < E) {
            int d = dst[e];
            pk[k] = d >> PSH;
            rec[k] = ((unsigned int)(d & (PNODES - 1)) << 20) | (unsigned int)src[e];
            atomicAdd(&cnt[pk[k]], 1);
        } else pk[k] = -1;
    }
    __syncthreads();
    for (int i = tid; i < np; i += 256)
        if (cnt[i]) gb[i] = atomicAdd(&pcursor[i * CURPAD], cnt[i]);
    __syncthreads();
#pragma unroll
    for (int k = 0; k < 16; ++k) {
        if (pk[k] >= 0) {
            int off = atomicAdd(&loc[pk[k]], 1);
            barr[gb[pk[k]] + off] = rec[k];
        }
    }
}

// Block per partition: LDS counting sort -> node-sorted csr + row_start.
__global__ __launch_bounds__(256) void k_psort(const unsigned int* __restrict__ barr,
        const int* __restrict__ pstart, int* __restrict__ csr,
        int* __restrict__ row_start, int n, int np, int E) {
    __shared__ int hist[PNODES], curs[PNODES], tsum[256];
    int tid = threadIdx.x;
    int p = blockIdx.x;
    int e0 = pstart[p], e1 = pstart[p + 1];
    int node0 = p << PSH;
#pragma unroll
    for (int j = 0; j < PNODES / 256; ++j) hist[tid + j * 256] = 0;
    __syncthreads();
    for (int t = e0 + tid; t < e1; t += 256)
        atomicAdd(&hist[barr[t] >> 20], 1);
    __syncthreads();
    // block scan over PNODES=1024 entries (4 per thread)
    int s0 = hist[tid * 4], s1 = hist[tid * 4 + 1], s2 = hist[tid * 4 + 2], s3 = hist[tid * 4 + 3];
    int sum4 = s0 + s1 + s2 + s3;
    tsum[tid] = sum4; __syncthreads();
    for (int o = 1; o < 256; o <<= 1) {
        int u = (tid >= o) ? tsum[tid - o] : 0;
        __syncthreads(); tsum[tid] += u; __syncthreads();
    }
    int bexc = tsum[tid] - sum4;
    int off0 = bexc, off1 = bexc + s0, off2 = off1 + s1, off3 = off2 + s2;
    curs[tid * 4] = off0; curs[tid * 4 + 1] = off1;
    curs[tid * 4 + 2] = off2; curs[tid * 4 + 3] = off3;
    int nd = node0 + tid * 4;
    if (nd < n)     row_start[nd]     = e0 + off0;
    if (nd + 1 < n) row_start[nd + 1] = e0 + off1;
    if (nd + 2 < n) row_start[nd + 2] = e0 + off2;
    if (nd + 3 < n) row_start[nd + 3] = e0 + off3;
    if (p == np - 1 && tid == 0) row_start[n] = E;
    __syncthreads();
    for (int t = e0 + tid; t < e1; t += 256) {
        unsigned int rec = barr[t];
        int pos = atomicAdd(&curs[rec >> 20], 1);
        csr[e0 + pos] = (int)(rec & 0xFFFFF);
    }
}

// ------------- aggregation 0 (pull, wave/node, dwordx4 slot gathers) ------
template<bool BF>
__device__ __forceinline__ void agg0_impl(const void* x, const int* rs, const int* csr,
                                          u16* agg, int n) {
    int i = blockIdx.x * 4 + (threadIdx.x >> 6);
    if (i >= n) return;
    int lane = threadIdx.x & 63;
    int b = rs[i], e = rs[i + 1];
    if (BF) {
        // x row = 64 bf16 = 128B = 8 lanes x 16B ; 8 edge slots per wave
        int slot = lane >> 3, cp = lane & 7;
        float acc[8] = {0.f, 0.f, 0.f, 0.f, 0.f, 0.f, 0.f, 0.f};
        int t = b + slot;
        for (; t + 8 < e; t += 16) {
            int j0 = csr[t], j1 = csr[t + 8];
            uint4 w0 = *((const uint4*)((const unsigned int*)x + (long)j0 * 32) + cp);
            uint4 w1 = *((const uint4*)((const unsigned int*)x + (long)j1 * 32) + cp);
            acc[0] += lo16(w0.x); acc[1] += hi16(w0.x);
            acc[2] += lo16(w0.y); acc[3] += hi16(w0.y);
            acc[4] += lo16(w0.z); acc[5] += hi16(w0.z);
            acc[6] += lo16(w0.w); acc[7] += hi16(w0.w);
            acc[0] += lo16(w1.x); acc[1] += hi16(w1.x);
            acc[2] += lo16(w1.y); acc[3] += hi16(w1.y);
            acc[4] += lo16(w1.z); acc[5] += hi16(w1.z);
            acc[6] += lo16(w1.w); acc[7] += hi16(w1.w);
        }
        if (t < e) {
            int j0 = csr[t];
            uint4 w0 = *((const uint4*)((const unsigned int*)x + (long)j0 * 32) + cp);
            acc[0] += lo16(w0.x); acc[1] += hi16(w0.x);
            acc[2] += lo16(w0.y); acc[3] += hi16(w0.y);
            acc[4] += lo16(w0.z); acc[5] += hi16(w0.z);
            acc[6] += lo16(w0.w); acc[7] += hi16(w0.w);
        }
#pragma unroll
        for (int k = 0; k < 8; ++k) {
            acc[k] += __shfl_xor(acc[k], 8);
            acc[k] += __shfl_xor(acc[k], 16);
            acc[k] += __shfl_xor(acc[k], 32);
        }
        if (slot == 0) {
            uint4 o;
            o.x = (unsigned int)f2bf(acc[0]) | ((unsigned int)f2bf(acc[1]) << 16);
            o.y = (unsigned int)f2bf(acc[2]) | ((unsigned int)f2bf(acc[3]) << 16);
            o.z = (unsigned int)f2bf(acc[4]) | ((unsigned int)f2bf(acc[5]) << 16);
            o.w = (unsigned int)f2bf(acc[6]) | ((unsigned int)f2bf(acc[7]) << 16);
            *((uint4*)((unsigned int*)agg + (long)i * 32) + cp) = o;
        }
    } else {
        // x row = 64 f32 = 256B = 16 lanes x 16B ; 4 edge slots per wave
        int slot = lane >> 4, cp = lane & 15;
        float acc[4] = {0.f, 0.f, 0.f, 0.f};
        int t = b + slot;
        for (; t + 4 < e; t += 8) {
            int j0 = csr[t], j1 = csr[t + 4];
            float4 w0 = *((const float4*)((const float*)x + (long)j0 * 64) + cp);
            float4 w1 = *((const float4*)((const float*)x + (long)j1 * 64) + cp);
            acc[0] += w0.x + w1.x; acc[1] += w0.y + w1.y;
            acc[2] += w0.z + w1.z; acc[3] += w0.w + w1.w;
        }
        if (t < e) {
            int j0 = csr[t];
            float4 w0 = *((const float4*)((const float*)x + (long)j0 * 64) + cp);
            acc[0] += w0.x; acc[1] += w0.y; acc[2] += w0.z; acc[3] += w0.w;
        }
#pragma unroll
        for (int k = 0; k < 4; ++k) {
            acc[k] += __shfl_xor(acc[k], 16);
            acc[k] += __shfl_xor(acc[k], 32);
        }
        if (slot == 0) {
            unsigned int o0 = (unsigned int)f2bf(acc[0]) | ((unsigned int)f2bf(acc[1]) << 16);
            unsigned int o1 = (unsigned int)f2bf(acc[2]) | ((unsigned int)f2bf(acc[3]) << 16);
            uint2 o; o.x = o0; o.y = o1;
            *((uint2*)((unsigned int*)agg + (long)i * 32) + cp) = o;
        }
    }
}

__global__ __launch_bounds__(256) void k_agg0(const int* __restrict__ flag,
        const void* x, const int* __restrict__ rs, const int* __restrict__ csr,
        u16* __restrict__ agg, int n) {
    if (*flag) agg0_impl<true >(x, rs, csr, agg, n);
    else       agg0_impl<false>(x, rs, csr, agg, n);
}

// ---- y0p = relu(bn0(y0)) materialized IN-PLACE (bf16), streaming --------
__global__ __launch_bounds__(256) void k_y0p(unsigned int* __restrict__ y0,
        const float* __restrict__ sc, const float* __restrict__ sh, long nq) {
    // nq = N*16 uint4-quads; thread's column-quad is fixed (stride % 16 == 0)
    long idx = (long)blockIdx.x * 256 + threadIdx.x;
    int colq = threadIdx.x & 15;
    float s8[8], h8[8];
#pragma unroll
    for (int j = 0; j < 8; ++j) { s8[j] = sc[colq * 8 + j]; h8[j] = sh[colq * 8 + j]; }
    long stride = (long)gridDim.x * 256;
    uint4* p = (uint4*)y0;
    for (; idx < nq; idx += stride) {
        uint4 w = p[idx];
        unsigned int r[4] = {w.x, w.y, w.z, w.w};
        uint4 o;
        unsigned int* po = (unsigned int*)&o;
#pragma unroll
        for (int d = 0; d < 4; ++d) {
            float a = fmaxf(lo16(r[d]) * s8[2 * d]     + h8[2 * d],     0.f);
            float b = fmaxf(hi16(r[d]) * s8[2 * d + 1] + h8[2 * d + 1], 0.f);
            po[d] = (unsigned int)f2bf(a) | ((unsigned int)f2bf(b) << 16);
        }
        p[idx] = o;
    }
}

// ------------- aggregation 1 (pure bf16 gather-sum of y0p rows) -----------
__global__ __launch_bounds__(256) void k_agg1(const u16* __restrict__ y0p,
        const int* __restrict__ rs, const int* __restrict__ csr,
        u16* __restrict__ agg, int n) {
    int i = blockIdx.x * 4 + (threadIdx.x >> 6);
    if (i >= n) return;
    int lane = threadIdx.x & 63;
    // y0p row = 128 bf16 = 256B = 16 lanes x 16B ; 4 edge slots per wave
    int slot = lane >> 4, cp = lane & 15;
    const unsigned int* y32 = (const unsigned int*)y0p;
    int b = rs[i], e = rs[i + 1];
    float acc[8] = {0.f, 0.f, 0.f, 0.f, 0.f, 0.f, 0.f, 0.f};
    int t = b + slot;
    for (; t + 4 < e; t += 8) {
        int j0 = csr[t], j1 = csr[t + 4];
        uint4 w0 = *((const uint4*)(y32 + (long)j0 * 64) + cp);
        uint4 w1 = *((const uint4*)(y32 + (long)j1 * 64) + cp);
        acc[0] += lo16(w0.x); acc[1] += hi16(w0.x);
        acc[2] += lo16(w0.y); acc[3] += hi16(w0.y);
        acc[4] += lo16(w0.z); acc[5] += hi16(w0.z);
        acc[6] += lo16(w0.w); acc[7] += hi16(w0.w);
        acc[0] += lo16(w1.x); acc[1] += hi16(w1.x);
        acc[2] += lo16(w1.y); acc[3] += hi16(w1.y);
        acc[4] += lo16(w1.z); acc[5] += hi16(w1.z);
        acc[6] += lo16(w1.w); acc[7] += hi16(w1.w);
    }
    if (t < e) {
        int j0 = csr[t];
        uint4 w0 = *((const uint4*)(y32 + (long)j0 * 64) + cp);
        acc[0] += lo16(w0.x); acc[1] += hi16(w0.x);
        acc[2] += lo16(w0.y); acc[3] += hi16(w0.y);
        acc[4] += lo16(w0.z); acc[5] += hi16(w0.z);
        acc[6] += lo16(w0.w); acc[7] += hi16(w0.w);
    }
#pragma unroll
    for (int k = 0; k < 8; ++k) {
        acc[k] += __shfl_xor(acc[k], 16);
        acc[k] += __shfl_xor(acc[k], 32);
    }
    if (slot == 0) {
        uint4 o;
        o.x = (unsigned int)f2bf(acc[0]) | ((unsigned int)f2bf(acc[1]) << 16);
        o.y = (unsigned int)f2bf(acc[2]) | ((unsigned int)f2bf(acc[3]) << 16);
        o.z = (unsigned int)f2bf(acc[4]) | ((unsigned int)f2bf(acc[5]) << 16);
        o.w = (unsigned int)f2bf(acc[6]) | ((unsigned int)f2bf(acc[7]) << 16);
        *((uint4*)((unsigned int*)agg + (long)i * 64) + cp) = o;
    }
}

// ---------------- GEMM0: y0 = [x|agg0] @ [Wr0;Wn0]^T, fused stats ----------
// Persistent grid-stride; stats in regs; one padded atomic per channel/block.
template<bool BF>
__device__ __forceinline__ void gemm0_impl(const void* x, const u16* agg,
                                           const void* Wr, const void* Wn,
                                           u16* y0, float* sumP, float* sqP,
                                           int n, int nch, u16* lds) {
    const int ST = 130;
    int tid = threadIdx.x;
    int wave = tid >> 6, lane = tid & 63, lr = lane & 15, q = lane >> 4;

    short8 wf[2][4];
#pragma unroll
    for (int i = 0; i < 2; ++i) {
        int c = (2 * wave + i) * 16 + lr;
#pragma unroll
        for (int ks = 0; ks < 4; ++ks) {
            const void* W = (ks < 2) ? Wr : Wn;
            wf[i][ks] = ld8<BF>(W, (long)c * CIN + (ks & 1) * 32 + q * 8);
        }
    }

    const int rowb = tid >> 3, wb = tid & 7;    // bf16 64-wide rows: 2/thread
    const int rowf = tid >> 4, wfc = tid & 15;  // f32 64-wide rows: 4/thread
    short8 rbx[2]; float4 rfx[4]; short8 rag[2];

    auto regload = [&](long chunk0) {
        if (BF) {
#pragma unroll
            for (int i = 0; i < 2; ++i) {
                long rg = chunk0 + rowb + i * 32; if (rg > n - 1) rg = n - 1;
                rbx[i] = *(const short8*)((const u16*)x + rg * CIN + wb * 8);
            }
        } else {
#pragma unroll
            for (int i = 0; i < 4; ++i) {
                long rg = chunk0 + rowf + i * 16; if (rg > n - 1) rg = n - 1;
                rfx[i] = *(const float4*)((const float*)x + rg * CIN + wfc * 4);
            }
        }
#pragma unroll
        for (int i = 0; i < 2; ++i) {
            long rg = chunk0 + rowb + i * 32; if (rg > n - 1) rg = n - 1;
            rag[i] = *(const short8*)(agg + rg * CIN + wb * 8);
        }
    };

    float st[2] = {0.f, 0.f}, sq[2] = {0.f, 0.f};
    int ch = blockIdx.x;
    if (ch < nch) regload((long)ch * 64);
    for (; ch < nch; ch += gridDim.x) {
        long chunk0 = (long)ch * 64;
        __syncthreads();                        // prev compute done with LDS
        if (BF) {
#pragma unroll
            for (int i = 0; i < 2; ++i)
                *(short8*)(lds + (rowb + i * 32) * ST + wb * 8) = rbx[i];
        } else {
#pragma unroll
            for (int i = 0; i < 4; ++i) {
                u16* d = lds + (rowf + i * 16) * ST + wfc * 4;
                d[0] = f2bf(rfx[i].x); d[1] = f2bf(rfx[i].y);
                d[2] = f2bf(rfx[i].z); d[3] = f2bf(rfx[i].w);
            }
        }
#pragma unroll
        for (int i = 0; i < 2; ++i)
            *(short8*)(lds + (rowb + i * 32) * ST + 64 + wb * 8) = rag[i];
        __syncthreads();
        long nxt = (long)ch + gridDim.x;        // T14: issue next loads now
        if (nxt < nch) regload(nxt * 64);

#pragma unroll
        for (int t = 0; t < 4; ++t) {
            short8 a[4];
#pragma unroll
            for (int ks = 0; ks < 4; ++ks)
                a[ks] = *(const short8*)(lds + (t * 16 + lr) * ST + ks * 32 + q * 8);
#pragma unroll
            for (int i = 0; i < 2; ++i) {
                f32x4 acc = {0.f, 0.f, 0.f, 0.f};
#pragma unroll
                for (int ks = 0; ks < 4; ++ks)
                    acc = __builtin_amdgcn_mfma_f32_16x16x32_bf16(a[ks], wf[i][ks], acc, 0, 0, 0);
                int c = (2 * wave + i) * 16 + lr;
#pragma unroll
                for (int r = 0; r < 4; ++r) {
                    long row = chunk0 + t * 16 + q * 4 + r;
                    if (row < n) {
                        y0[row * COUT + c] = f2bf(acc[r]);   // b0 cancels in BN
                        st[i] += acc[r]; sq[i] += acc[r] * acc[r];
                    }
                }
            }
        }
    }
#pragma unroll
    for (int i = 0; i < 2; ++i) {
        st[i] += __shfl_xor(st[i], 16); st[i] += __shfl_xor(st[i], 32);
        sq[i] += __shfl_xor(sq[i], 16); sq[i] += __shfl_xor(sq[i], 32);
    }
    if (q == 0) {
#pragma unroll
        for (int i = 0; i < 2; ++i) {
            int c = (2 * wave + i) * 16 + lr;
            atomicAdd(&sumP[c * SPAD], st[i]);
            atomicAdd(&sqP[c * SPAD], sq[i]);
        }
    }
}

__global__ __launch_bounds__(256) void k_gemm0(const int* __restrict__ flag,
        const void* x, const u16* __restrict__ agg, const void* Wr, const void* Wn,
        u16* __restrict__ y0, float* __restrict__ sumP, float* __restrict__ sqP,
        int n, int nch) {
    __shared__ u16 lds[64 * 130];
    if (*flag) gemm0_impl<true >(x, agg, Wr, Wn, y0, sumP, sqP, n, nch, lds);
    else       gemm0_impl<false>(x, agg, Wr, Wn, y0, sumP, sqP, n, nch, lds);
}

// ---------------- GEMM1: y1 = [y0p|agg1] @ [Wr1;Wn1]^T, fused stats -------
template<bool BF>
__device__ __forceinline__ void gemm1_impl(const u16* y0p, const u16* agg,
                                           const void* Wr, const void* Wn,
                                           u16* y1, float* sumP, float* sqP,
                                           int n, int nch, u16* lds) {
    const int ST = 258;
    int tid = threadIdx.x;
    int wave = tid >> 6, lane = tid & 63, lr = lane & 15, q = lane >> 4;

    short8 wf[2][8];
#pragma unroll
    for (int i = 0; i < 2; ++i) {
        int c = (2 * wave + i) * 16 + lr;
#pragma unroll
        for (int ks = 0; ks < 8; ++ks) {
            const void* W = (ks < 4) ? Wr : Wn;
            wf[i][ks] = ld8<BF>(W, (long)c * COUT + (ks & 3) * 32 + q * 8);
        }
    }

    const int rowy = tid >> 4, wy = tid & 15;   // 128-wide rows: 4/thread
    short8 ry[4], rag[4];
    auto regload = [&](long chunk0) {
#pragma unroll
        for (int i = 0; i < 4; ++i) {
            long rg = chunk0 + rowy + i * 16; if (rg > n - 1) rg = n - 1;
            ry[i]  = *(const short8*)(y0p + rg * COUT + wy * 8);
            rag[i] = *(const short8*)(agg + rg * COUT + wy * 8);
        }
    };

    float st[2] = {0.f, 0.f}, sq[2] = {0.f, 0.f};
    int ch = blockIdx.x;
    if (ch < nch) regload((long)ch * 64);
    for (; ch < nch; ch += gridDim.x) {
        long chunk0 = (long)ch * 64;
        __syncthreads();
#pragma unroll
        for (int i = 0; i < 4; ++i) {
            *(short8*)(lds + (rowy + i * 16) * ST + wy * 8) = ry[i];
            *(short8*)(lds + (rowy + i * 16) * ST + 128 + wy * 8) = rag[i];
        }
        __syncthreads();
        long nxt = (long)ch + gridDim.x;
        if (nxt < nch) regload(nxt * 64);

#pragma unroll
        for (int t = 0; t < 4; ++t) {
            short8 a[8];
#pragma unroll
            for (int ks = 0; ks < 8; ++ks)
                a[ks] = *(const short8*)(lds + (t * 16 + lr) * ST + ks * 32 + q * 8);
#pragma unroll
            for (int i = 0; i < 2; ++i) {
                f32x4 acc = {0.f, 0.f, 0.f, 0.f};
#pragma unroll
                for (int ks = 0; ks < 8; ++ks)
                    acc = __builtin_amdgcn_mfma_f32_16x16x32_bf16(a[ks], wf[i][ks], acc, 0, 0, 0);
                int c = (2 * wave + i) * 16 + lr;
#pragma unroll
                for (int r = 0; r < 4; ++r) {
                    long row = chunk0 + t * 16 + q * 4 + r;
                    if (row < n) {
                        y1[row * COUT + c] = f2bf(acc[r]);   // b1 cancels in BN
                        st[i] += acc[r]; sq[i] += acc[r] * acc[r];
                    }
                }
            }
        }
    }
#pragma unroll
    for (int i = 0; i < 2; ++i) {
        st[i] += __shfl_xor(st[i], 16); st[i] += __shfl_xor(st[i], 32);
        sq[i] += __shfl_xor(sq[i], 16); sq[i] += __shfl_xor(sq[i], 32);
    }
    if (q == 0) {
#pragma unroll
        for (int i = 0; i < 2; ++i) {
            int c = (2 * wave + i) * 16 + lr;
            atomicAdd(&sumP[c * SPAD], st[i]);
            atomicAdd(&sqP[c * SPAD], sq[i]);
        }
    }
}

__global__ __launch_bounds__(256) void k_gemm1(const int* __restrict__ flag,
        const u16* __restrict__ y0p, const u16* __restrict__ agg,
        const void* Wr, const void* Wn,
        u16* y1_bf /*=d_out*/, u16* y1_ws,
        float* __restrict__ sumP, float* __restrict__ sqP, int n, int nch) {
    __shared__ u16 lds[64 * 258];
    u16* y1 = *flag ? y1_bf : y1_ws;
    if (*flag) gemm1_impl<true >(y0p, agg, Wr, Wn, y1, sumP, sqP, n, nch, lds);
    else       gemm1_impl<false>(y0p, agg, Wr, Wn, y1, sumP, sqP, n, nch, lds);
}

// ---------------- BN finalize (reads line-padded stats) ----------------
__global__ void k_bnfin(const int* __restrict__ flag,
                        const float* __restrict__ sumP, const float* __restrict__ sqP,
                        const void* g, const void* be,
                        float* __restrict__ scale, float* __restrict__ shift, int n) {
    int c = threadIdx.x;
    bool bf = (*flag != 0);
    float inv = 1.f / (float)n;
    float mu = sumP[c * SPAD] * inv;
    float var = fmaxf(sqP[c * SPAD] * inv - mu * mu, 0.f);
    float gv = bf ? bf2f(((const u16*)g)[c]) : ((const float*)g)[c];
    float bv = bf ? bf2f(((const u16*)be)[c]) : ((const float*)be)[c];
    float sc = gv * rsqrtf(var + BN_EPS);
    scale[c] = sc;
    shift[c] = bv - mu * sc;
}

// ---------------- final: out = relu(bn1(y1) + x@Wlin^T + blin) ------------
template<bool BF>
__device__ __forceinline__ void final_impl(const void* x, const u16* y1,
                                           const void* Wlin, const void* blin,
                                           const float* sc, const float* sh,
                                           void* out, int n, int nch, u16* lds) {
    const int ST = 194;
    int tid = threadIdx.x;
    int wave = tid >> 6, lane = tid & 63, lr = lane & 15, q = lane >> 4;

    short8 wf[2][2];
    float blc[2], scc[2], shc[2];
#pragma unroll
    for (int i = 0; i < 2; ++i) {
        int c = (2 * wave + i) * 16 + lr;
#pragma unroll
        for (int ks = 0; ks < 2; ++ks)
            wf[i][ks] = ld8<BF>(Wlin, (long)c * CIN + ks * 32 + q * 8);
        blc[i] = ldf<BF>(blin, c);
        scc[i] = sc[c]; shc[i] = sh[c];
    }

    const int rowb = tid >> 3, wb = tid & 7;
    const int rowf = tid >> 4, wfc = tid & 15;
    const int rowy = tid >> 4, wy = tid & 15;
    short8 rbx[2]; float4 rfx[4]; short8 ry[4];

    auto regload = [&](long chunk0) {
        if (BF) {
#pragma unroll
            for (int i = 0; i < 2; ++i) {
                long rg = chunk0 + rowb + i * 32; if (rg > n - 1) rg = n - 1;
                rbx[i] = *(const short8*)((const u16*)x + rg * CIN + wb * 8);
            }
        } else {
#pragma unroll
            for (int i = 0; i < 4; ++i) {
                long rg = chunk0 + rowf + i * 16; if (rg > n - 1) rg = n - 1;
                rfx[i] = *(const float4*)((const float*)x + rg * CIN + wfc * 4);
            }
        }
#pragma unroll
        for (int i = 0; i < 4; ++i) {
            long rg = chunk0 + rowy + i * 16; if (rg > n - 1) rg = n - 1;
            ry[i] = *(const short8*)(y1 + rg * COUT + wy * 8);
        }
    };

    int ch = blockIdx.x;
    if (ch < nch) regload((long)ch * 64);
    for (; ch < nch; ch += gridDim.x) {
        long chunk0 = (long)ch * 64;
        __syncthreads();
        if (BF) {
#pragma unroll
            for (int i = 0; i < 2; ++i)
                *(short8*)(lds + (rowb + i * 32) * ST + wb * 8) = rbx[i];
        } else {
#pragma unroll
            for (int i = 0; i < 4; ++i) {
                u16* d = lds + (rowf + i * 16) * ST + wfc * 4;
                d[0] = f2bf(rfx[i].x); d[1] = f2bf(rfx[i].y);
                d[2] = f2bf(rfx[i].z); d[3] = f2bf(rfx[i].w);
            }
        }
#pragma unroll
        for (int i = 0; i < 4; ++i)
            *(short8*)(lds + (rowy + i * 16) * ST + 64 + wy * 8) = ry[i];
        __syncthreads();
        long nxt = (long)ch + gridDim.x;
        if (nxt < nch) regload(nxt * 64);

#pragma unroll
        for (int t = 0; t < 4; ++t) {
            short8 a[2];
#pragma unroll
            for (int ks = 0; ks < 2; ++ks)
                a[ks] = *(const short8*)(lds + (t * 16 + lr) * ST + ks * 32 + q * 8);
#pragma unroll
            for (int i = 0; i < 2; ++i) {
                f32x4 acc = {0.f, 0.f, 0.f, 0.f};
                acc = __builtin_amdgcn_mfma_f32_16x16x32_bf16(a[0], wf[i][0], acc, 0, 0, 0);
                acc = __builtin_amdgcn_mfma_f32_16x16x32_bf16(a[1], wf[i][1], acc, 0, 0, 0);
                int c = (2 * wave + i) * 16 + lr;
#pragma unroll
                for (int r = 0; r < 4; ++r) {
                    long row = chunk0 + t * 16 + q * 4 + r;
                    if (row < n) {
                        float yv = bf2f(lds[(t * 16 + q * 4 + r) * ST + 64 + c]);
                        float v = acc[r] + blc[i] + yv * scc[i] + shc[i];
                        v = fmaxf(v, 0.f);
                        if (BF) ((u16*)out)[row * COUT + c] = f2bf(v);
                        else    ((float*)out)[row * COUT + c] = v;
                    }
                }
            }
        }
    }
}

__global__ __launch_bounds__(256) void k_final(const int* __restrict__ flag,
        const void* x, const void* Wlin, const void* blin,
        const u16* y1_bf /*=d_out*/, const u16* y1_ws,
        const float* __restrict__ sc, const float* __restrict__ sh,
        void* out, int n, int nch) {
    __shared__ u16 lds[64 * 194];
    const u16* y1 = *flag ? y1_bf : y1_ws;
    if (*flag) final_impl<true >(x, y1, Wlin, blin, sc, sh, out, n, nch, lds);
    else       final_impl<false>(x, y1, Wlin, blin, sc, sh, out, n, nch, lds);
}

extern "C" void kernel_launch(void* const* d_in, const int* in_sizes, int n_in,
                              void* d_out, int out_size, void* d_ws, size_t ws_size,
                              hipStream_t stream) {
    (void)n_in; (void)out_size; (void)ws_size;
    const void* x    = d_in[0];
    const int*  ei   = (const int*)d_in[1];
    const void* Wr0  = d_in[2];
    const void* Wn0  = d_in[3];
    /* b0 dropped: BN-invariant */
    const void* g0   = d_in[5];
    const void* be0  = d_in[6];
    const void* Wr1  = d_in[7];
    const void* Wn1  = d_in[8];
    /* b1 dropped */
    const void* g1   = d_in[10];
    const void* be1  = d_in[11];
    const void* Wlin = d_in[12];
    const void* blin = d_in[13];

    const int N = in_sizes[0] / CIN;
    const int E = in_sizes[1] / 2;
    const int* src = ei;
    const int* dst = ei + E;
    const int NP = (N + PNODES - 1) >> PSH;   // partitions (<= MAXP for N <= 131072)

    // ---- workspace carve (256B aligned); f32-only region LAST ----
    char* base = (char*)d_ws;
    size_t off = 0;
    auto carve = [&](size_t bytes) -> void* {
        void* p = base + off;
        off = (off + bytes + 255) & ~(size_t)255;
        return p;
    };
    int*   flag      = (int*)carve(256);
    int*   pcount    = (int*)carve(MAXP * PCPAD * sizeof(int));
    int*   pstart    = (int*)carve((MAXP + 1) * sizeof(int));
    int*   pcursor   = (int*)carve(MAXP * CURPAD * sizeof(int));
    float* statsP    = (float*)carve(4 * 128 * SPAD * sizeof(float)); // padded sum0,sq0,sum1,sq1
    float* scsh      = (float*)carve(512 * sizeof(float));  // scale0,shift0,scale1,shift1
    int*   row_start = (int*)carve((size_t)(N + 1) * sizeof(int));
    unsigned int* barr = (unsigned int*)carve((size_t)E * sizeof(int));
    int*   csr       = (int*)carve((size_t)E * sizeof(int));
    u16*   aggu      = (u16*)carve((size_t)N * COUT * sizeof(u16)); // agg0 aliases agg1
    u16*   y0        = (u16*)carve((size_t)N * COUT * sizeof(u16));
    u16*   y1_ws     = (u16*)carve((size_t)N * COUT * sizeof(u16)); // f32 mode only

    float* sum0P = statsP;
    float* sq0P  = statsP + 128 * SPAD;
    float* sum1P = statsP + 256 * SPAD;
    float* sq1P  = statsP + 384 * SPAD;

    hipMemsetAsync(pcount, 0, MAXP * PCPAD * sizeof(int), stream);
    hipMemsetAsync(statsP, 0, 4 * 128 * SPAD * sizeof(float), stream);

    const int nwb = (N + 3) / 4;        // wave-per-node blocks
    const int nch = (N + 63) / 64;      // 64-row chunks for dense kernels
    const int ntl = (E + 4095) / 4096;  // pfill tiles
    const int G   = nch < 1024 ? nch : 1024;  // persistent gemm grid
    const long nq = (long)N * 16;       // y0 uint4-quads
    int g2 = (int)((nq + 255) / 256); if (g2 > 2048) g2 = 2048;

    k_detect<<<1, 64, 0, stream>>>((const unsigned int*)x, flag);

    k_phist<<<256, 256, 0, stream>>>(dst, pcount, E, NP);
    k_pscan<<<1, MAXP, 0, stream>>>(pcount, pstart, pcursor, NP, E);
    k_pfill<<<ntl, 256, 0, stream>>>(src, dst, pcursor, barr, E, NP);
    k_psort<<<NP, 256, 0, stream>>>(barr, pstart, csr, row_start, N, NP, E);

    k_agg0 <<<nwb, 256, 0, stream>>>(flag, x, row_start, csr, aggu, N);
    k_gemm0<<<G, 256, 0, stream>>>(flag, x, aggu, Wr0, Wn0, y0,
                                   sum0P, sq0P, N, nch);
    k_bnfin<<<1, 128, 0, stream>>>(flag, sum0P, sq0P, g0, be0,
                                   scsh, scsh + 128, N);

    k_y0p<<<g2, 256, 0, stream>>>((unsigned int*)y0, scsh, scsh + 128, nq);

    k_agg1 <<<nwb, 256, 0, stream>>>(y0, row_start, csr, aggu, N);
    k_gemm1<<<G, 256, 0, stream>>>(flag, y0, aggu, Wr1, Wn1,
                                   (u16*)d_out, y1_ws, sum1P, sq1P, N, nch);
    k_bnfin<<<1, 128, 0, stream>>>(flag, sum1P, sq1P, g1, be1,
                                   scsh + 256, scsh + 384, N);

    k_final<<<G, 256, 0, stream>>>(flag, x, Wlin, blin,
                                   (const u16*)d_out, y1_ws,
                                   scsh + 256, scsh + 384, d_out, N, nch);
}